// Round 3
// baseline (669.982 us; speedup 1.0000x reference)
//
#include <hip/hip_runtime.h>
#include <hip/hip_bf16.h>

typedef __bf16 bf16_t;
typedef __attribute__((ext_vector_type(8))) __bf16 bf16x8;
typedef __attribute__((ext_vector_type(4))) __bf16 bf16x4;
typedef __attribute__((ext_vector_type(4))) float fx4;

#define GLDS(g, l)                                                              \
  __builtin_amdgcn_global_load_lds(                                             \
      (const __attribute__((address_space(1))) void*)(g),                       \
      (__attribute__((address_space(3))) void*)(l), 16, 0, 0)

enum { EPI_F32 = 0, EPI_BF16 = 1, EPI_HILO = 2, EPI_FUSE = 3 };

// ---------------------------------------------------------------------------
// BT-layout GEMM with optional 3-segment split-bf16 accumulation:
//   NSEG=1: C = A1·B1^T
//   NSEG=3: C = A1·B1^T + A2·B1^T + A1·B2^T   (hi/lo split: ~fp32 precision)
// A: [M,K] row-major, B: [N,K] row-major. Tile 128x128, BK=32, 4 waves.
// EPI: F32 store | BF16 store | HILO (split C into hi/lo bf16) | FUSE
// (out = resid + relu(acc + bias[n]), fp32).
// ---------------------------------------------------------------------------
template <int NSEG, int EPI>
__global__ __launch_bounds__(256) void gemm_bt(
    const bf16_t* __restrict__ A1, const bf16_t* __restrict__ A2,
    const bf16_t* __restrict__ B1, const bf16_t* __restrict__ B2,
    void* __restrict__ Cv, void* __restrict__ C2v, int K,
    long long sA, long long sB, long long sC,
    const float* __restrict__ bias, const float* __restrict__ resid,
    long long sR) {
  __shared__ __align__(16) bf16_t As[128 * 32];
  __shared__ __align__(16) bf16_t Bs[128 * 32];

  const int tid  = threadIdx.x;
  const int lane = tid & 63;
  const int w    = tid >> 6;
  const int wr   = w >> 1;
  const int wc   = w & 1;

  const int N = (int)gridDim.x * 128;
  const long long tile_m = (long long)blockIdx.y * 128;
  const long long tile_n = (long long)blockIdx.x * 128;
  const long long z = blockIdx.z;
  const long long aoff = z * sA + tile_m * (long long)K;
  const long long boff = z * sB + tile_n * (long long)K;

  fx4 acc[4][4];
#pragma unroll
  for (int i = 0; i < 4; i++)
#pragma unroll
    for (int j = 0; j < 4; j++) acc[i][j] = (fx4){0.f, 0.f, 0.f, 0.f};

  const int r_l  = lane >> 2;
  const int c_l  = (lane & 3) << 3;
  const int qk   = (lane >> 4) << 3;
  const int frow = lane & 15;

#pragma unroll
  for (int seg = 0; seg < NSEG; seg++) {
    const bf16_t* A = ((NSEG == 3 && seg == 1) ? A2 : A1) + aoff;
    const bf16_t* B = ((NSEG == 3 && seg == 2) ? B2 : B1) + boff;
    for (int kt = 0; kt < K; kt += 32) {
      __syncthreads();  // previous compute done before overwriting LDS
      {
        const bf16_t* ga = A + kt;
        const bf16_t* gb = B + kt;
        GLDS(ga + (size_t)(w * 16 + r_l) * K + c_l,      &As[(w * 16) * 32]);
        GLDS(ga + (size_t)(64 + w * 16 + r_l) * K + c_l, &As[(64 + w * 16) * 32]);
        GLDS(gb + (size_t)(w * 16 + r_l) * K + c_l,      &Bs[(w * 16) * 32]);
        GLDS(gb + (size_t)(64 + w * 16 + r_l) * K + c_l, &Bs[(64 + w * 16) * 32]);
      }
      __syncthreads();  // barrier drains vmcnt(0): LDS ready

      bf16x8 af[4], bb[4];
#pragma unroll
      for (int mi = 0; mi < 4; mi++)
        af[mi] = *(const bf16x8*)&As[(wr * 64 + mi * 16 + frow) * 32 + qk];
#pragma unroll
      for (int ni = 0; ni < 4; ni++)
        bb[ni] = *(const bf16x8*)&Bs[(wc * 64 + ni * 16 + frow) * 32 + qk];
#pragma unroll
      for (int mi = 0; mi < 4; mi++)
#pragma unroll
        for (int ni = 0; ni < 4; ni++)
          acc[mi][ni] = __builtin_amdgcn_mfma_f32_16x16x32_bf16(
              af[mi], bb[ni], acc[mi][ni], 0, 0, 0);
    }
  }

  // Epilogue. C/D layout: col = lane&15, row = (lane>>4)*4 + reg  [m89/m91]
  const int er = (lane >> 4) * 4;
  const int ec = lane & 15;
  const long long crow = tile_m + wr * 64;
  const long long ccol = tile_n + wc * 64;

#pragma unroll
  for (int mi = 0; mi < 4; mi++)
#pragma unroll
    for (int j = 0; j < 4; j++) {
      const long long r = crow + mi * 16 + er + j;
#pragma unroll
      for (int ni = 0; ni < 4; ni++) {
        const long long cc = ccol + ni * 16 + ec;
        const long long idx = z * sC + r * N + cc;
        const float v = acc[mi][ni][j];
        if (EPI == EPI_F32) {
          ((float*)Cv)[idx] = v;
        } else if (EPI == EPI_BF16) {
          ((bf16_t*)Cv)[idx] = (bf16_t)v;
        } else if (EPI == EPI_HILO) {
          const bf16_t h = (bf16_t)v;
          ((bf16_t*)Cv)[idx] = h;
          ((bf16_t*)C2v)[idx] = (bf16_t)(v - (float)h);
        } else {  // EPI_FUSE
          float u = v + bias[cc];
          u = u > 0.f ? u : 0.f;
          ((float*)Cv)[idx] = resid[z * sR + r * N + cc] + u;
        }
      }
    }
}

// ---------------------------------------------------------------------------
// Row softmax over 2048 cols, diagonal mask at (m_base + row-within-batch).
// ---------------------------------------------------------------------------
__global__ __launch_bounds__(256) void softmax_rows(
    const float* __restrict__ s, bf16_t* __restrict__ a, int m_base) {
  __shared__ float red[8];
  const int row = blockIdx.x;
  const int m = m_base + (row & 2047);
  const float* sr = s + (long long)row * 2048;
  bf16_t* ar = a + (long long)row * 2048;

  const int lane = threadIdx.x & 63;
  const int w = threadIdx.x >> 6;

  float v[8];
  float mx = -1e30f;
#pragma unroll
  for (int j = 0; j < 8; j++) {
    const int t = threadIdx.x + j * 256;
    float x = sr[t];
    if (t == m) x = -1e30f;
    v[j] = x;
    mx = fmaxf(mx, x);
  }
  for (int o = 32; o > 0; o >>= 1) mx = fmaxf(mx, __shfl_down(mx, o, 64));
  if (lane == 0) red[w] = mx;
  __syncthreads();
  mx = fmaxf(fmaxf(red[0], red[1]), fmaxf(red[2], red[3]));

  float sum = 0.f;
#pragma unroll
  for (int j = 0; j < 8; j++) {
    const float e = __expf(v[j] - mx);
    v[j] = e;
    sum += e;
  }
  for (int o = 32; o > 0; o >>= 1) sum += __shfl_down(sum, o, 64);
  if (lane == 0) red[4 + w] = sum;
  __syncthreads();
  const float total = red[4] + red[5] + red[6] + red[7];
  const float inv = 1.0f / total;
#pragma unroll
  for (int j = 0; j < 8; j++)
    ar[threadIdx.x + j * 256] = (bf16_t)(v[j] * inv);
}

// ---------------------------------------------------------------------------
// Per-batch transpose: in [8][2048][768] bf16 -> out [8][768][2048] bf16
// ---------------------------------------------------------------------------
__global__ __launch_bounds__(256) void transpose_sd(
    const bf16_t* __restrict__ in, bf16_t* __restrict__ out) {
  __shared__ bf16_t t[32][33];
  const int b = blockIdx.z;
  const int d0 = blockIdx.x * 32;
  const int s0 = blockIdx.y * 32;
  const bf16_t* ib = in + (long long)b * 2048 * 768;
  bf16_t* ob = out + (long long)b * 2048 * 768;
  const int tx = threadIdx.x & 31;
  const int ty = threadIdx.x >> 5;
#pragma unroll
  for (int i = 0; i < 4; i++)
    t[ty + i * 8][tx] = ib[(long long)(s0 + ty + i * 8) * 768 + d0 + tx];
  __syncthreads();
#pragma unroll
  for (int i = 0; i < 4; i++)
    ob[(long long)(d0 + ty + i * 8) * 2048 + s0 + tx] = t[tx][ty + i * 8];
}

// ---------------------------------------------------------------------------
// fp32 -> (hi, lo) bf16 split, 4 elements per thread. x = hi + lo + O(2^-18)
// ---------------------------------------------------------------------------
__global__ __launch_bounds__(256) void split_hilo(
    const float* __restrict__ in, bf16_t* __restrict__ hi,
    bf16_t* __restrict__ lo, int n4) {
  const int i = blockIdx.x * 256 + threadIdx.x;
  if (i >= n4) return;
  const float4 v = ((const float4*)in)[i];
  const bf16_t h0 = (bf16_t)v.x, h1 = (bf16_t)v.y, h2 = (bf16_t)v.z,
               h3 = (bf16_t)v.w;
  ((bf16x4*)hi)[i] = (bf16x4){h0, h1, h2, h3};
  ((bf16x4*)lo)[i] = (bf16x4){(bf16_t)(v.x - (float)h0), (bf16_t)(v.y - (float)h1),
                              (bf16_t)(v.z - (float)h2), (bf16_t)(v.w - (float)h3)};
}

// ---------------------------------------------------------------------------
extern "C" void kernel_launch(void* const* d_in, const int* in_sizes, int n_in,
                              void* d_out, int out_size, void* d_ws,
                              size_t ws_size, hipStream_t stream) {
  const float* x  = (const float*)d_in[0];
  const float* W  = (const float*)d_in[1];
  const float* pw = (const float*)d_in[2];
  const float* pb = (const float*)d_in[3];

  const long long S = 2048, D = 768;
  const long long BS = 8 * S;  // 16384 rows

  // ---- fixed workspace (~81 MB) ----
  char* p = (char*)d_ws;
  auto carve = [&](long long bytes) {
    char* q = p;
    p += (bytes + 255) & ~255LL;
    return q;
  };
  bf16_t* xh = (bf16_t*)carve(BS * D * 2);  // x hi          25.2 MB
  bf16_t* xl = (bf16_t*)carve(BS * D * 2);  // x lo          25.2 MB
  bf16_t* xT = (bf16_t*)carve(BS * D * 2);  // x^T (hi)      25.2 MB
  bf16_t* Wh = (bf16_t*)carve(D * D * 2);   // W hi           1.2 MB
  bf16_t* Wl = (bf16_t*)carve(D * D * 2);   // W lo           1.2 MB
  bf16_t* ph = (bf16_t*)carve(D * D * 2);   // proj_w hi      1.2 MB
  bf16_t* pl = (bf16_t*)carve(D * D * 2);   // proj_w lo (unused downstream)
  const long long avail = (long long)ws_size - (long long)(p - (char*)d_ws);

  // ---- input splits + transpose ----
  split_hilo<<<(unsigned)(BS * D / 4 / 256), 256, 0, stream>>>(
      x, xh, xl, (int)(BS * D / 4));
  split_hilo<<<(unsigned)(D * D / 4 / 256), 256, 0, stream>>>(
      W, Wh, Wl, (int)(D * D / 4));
  split_hilo<<<(unsigned)(D * D / 4 / 256), 256, 0, stream>>>(
      pw, ph, pl, (int)(D * D / 4));
  transpose_sd<<<dim3(24, 64, 8), 256, 0, stream>>>(xh, xT);

  // per-batch chunk footprint: Wx hi+lo, s fp32, a bf16 (c aliases Wx_hi)
  const long long perb = 2 * S * D * 2 + S * S * 4 + S * S * 2;  // 30 MiB

  if (avail >= perb) {
    // ---- batch-chunk mode: nb batches at a time via blockIdx.z ----
    int nb = (int)(avail / perb);
    if (nb > 8) nb = 8;
    char* q = p;
    bf16_t* Wxh = (bf16_t*)q; q += (long long)nb * S * D * 2;
    bf16_t* Wxl = (bf16_t*)q; q += (long long)nb * S * D * 2;
    float*  sb  = (float*)q;  q += (long long)nb * S * S * 4;
    bf16_t* ab  = (bf16_t*)q;
    bf16_t* cc  = Wxh;  // c aliases Wx_hi (dead after GEMM2 of same chunk)

    for (int c0 = 0; c0 < 8; c0 += nb) {
      const int n = (8 - c0) < nb ? (8 - c0) : nb;
      // GEMM1: Wx = x @ W^T (3-seg split, hi/lo out)
      gemm_bt<3, EPI_HILO><<<dim3(6, 16, n), 256, 0, stream>>>(
          xh + (long long)c0 * S * D, xl + (long long)c0 * S * D, Wh, Wl,
          Wxh, Wxl, 768, S * D, 0, S * D, nullptr, nullptr, 0);
      // GEMM2: s = Wx @ x^T per batch (3-seg split, fp32 out)
      gemm_bt<3, EPI_F32><<<dim3(16, 16, n), 256, 0, stream>>>(
          Wxh, Wxl, xh + (long long)c0 * S * D, xl + (long long)c0 * S * D,
          sb, nullptr, 768, S * D, S * D, S * S, nullptr, nullptr, 0);
      softmax_rows<<<(unsigned)(n * S), 256, 0, stream>>>(sb, ab, 0);
      // GEMM3: c = a @ x (bf16 out)
      gemm_bt<1, EPI_BF16><<<dim3(6, 16, n), 256, 0, stream>>>(
          ab, nullptr, xT + (long long)c0 * D * S, nullptr, cc, nullptr, 2048,
          S * S, D * S, S * D, nullptr, nullptr, 0);
      // GEMM4: out = x + relu(c @ proj_w^T + pb)
      gemm_bt<1, EPI_FUSE><<<dim3(6, 16, n), 256, 0, stream>>>(
          cc, nullptr, ph, nullptr, (float*)d_out + (long long)c0 * S * D,
          nullptr, 768, S * D, 0, S * D, pb, x + (long long)c0 * S * D, S * D);
    }
  } else {
    // ---- row-chunk mode: R rows (multiple of 128) within one batch ----
    long long R = (avail / 15360) & ~127LL;  // bytes/row: 3072+3072(WxHL wait: hi+lo)+8192(s)+4096(a) = 15360 w/ c aliased
    if (R < 128) R = 128;
    if (R > 2048) R = 2048;
    char* q = p;
    bf16_t* Wxh = (bf16_t*)q; q += R * D * 2;
    bf16_t* Wxl = (bf16_t*)q; q += R * D * 2;
    float*  sb  = (float*)q;  q += R * S * 4;
    bf16_t* ab  = (bf16_t*)q;
    bf16_t* cc  = Wxh;

    for (int b = 0; b < 8; b++) {
      for (long long r0 = 0; r0 < S; r0 += R) {
        const long long rows = (S - r0) < R ? (S - r0) : R;
        const unsigned gy = (unsigned)(rows / 128);
        gemm_bt<3, EPI_HILO><<<dim3(6, gy, 1), 256, 0, stream>>>(
            xh + ((long long)b * S + r0) * D, xl + ((long long)b * S + r0) * D,
            Wh, Wl, Wxh, Wxl, 768, 0, 0, 0, nullptr, nullptr, 0);
        gemm_bt<3, EPI_F32><<<dim3(16, gy, 1), 256, 0, stream>>>(
            Wxh, Wxl, xh + (long long)b * S * D, xl + (long long)b * S * D,
            sb, nullptr, 768, 0, 0, 0, nullptr, nullptr, 0);
        softmax_rows<<<(unsigned)rows, 256, 0, stream>>>(sb, ab, (int)r0);
        gemm_bt<1, EPI_BF16><<<dim3(6, gy, 1), 256, 0, stream>>>(
            ab, nullptr, xT + (long long)b * D * S, nullptr, cc, nullptr, 2048,
            0, 0, 0, nullptr, nullptr, 0);
        gemm_bt<1, EPI_FUSE><<<dim3(6, gy, 1), 256, 0, stream>>>(
            cc, nullptr, ph, nullptr,
            (float*)d_out + ((long long)b * S + r0) * D, nullptr, 768,
            0, 0, 0, pb, x + ((long long)b * S + r0) * D, 0);
      }
    }
  }
}

// Round 4
// 598.467 us; speedup vs baseline: 1.1195x; 1.1195x over previous
//
#include <hip/hip_runtime.h>
#include <hip/hip_bf16.h>

typedef __bf16 bf16_t;
typedef __attribute__((ext_vector_type(8))) __bf16 bf16x8;
typedef __attribute__((ext_vector_type(4))) __bf16 bf16x4;
typedef __attribute__((ext_vector_type(4))) float fx4;

#define GLDS(g, l)                                                              \
  __builtin_amdgcn_global_load_lds(                                             \
      (const __attribute__((address_space(1))) void*)(g),                       \
      (__attribute__((address_space(3))) void*)(l), 16, 0, 0)

enum { EPI_F32 = 0, EPI_BF16 = 1, EPI_HILO = 2, EPI_FUSE = 3 };

// ---------------------------------------------------------------------------
// BT-layout GEMM, optionally with fused 3-term split-bf16 accumulation:
//   SPLIT=0: C = A1·B1^T
//   SPLIT=1: C = A1·B1^T + A2·B1^T + A1·B2^T  (hi/lo split ~fp32 precision)
// One K-loop; SPLIT stages 4 tiles (A_hi,A_lo,B_hi,B_lo = 32 KB LDS) per
// K-iter and issues 48 MFMAs per barrier pair (vs 16) — 3x barrier
// amortization, and hi operands staged once instead of twice.
// A: [M,K] row-major, B: [N,K] row-major. Tile 128x128, BK=32, 4 waves.
// ---------------------------------------------------------------------------
template <bool SPLIT, int EPI>
__global__ __launch_bounds__(256) void gemm_bt(
    const bf16_t* __restrict__ A1, const bf16_t* __restrict__ A2,
    const bf16_t* __restrict__ B1, const bf16_t* __restrict__ B2,
    void* __restrict__ Cv, void* __restrict__ C2v, int K,
    long long sA, long long sB, long long sC,
    const float* __restrict__ bias, const float* __restrict__ resid,
    long long sR) {
  constexpr int LO = SPLIT ? 128 * 32 : 0;  // lo-tile LDS offset
  __shared__ __align__(16) bf16_t As[128 * 32 + LO];
  __shared__ __align__(16) bf16_t Bs[128 * 32 + LO];

  const int tid  = threadIdx.x;
  const int lane = tid & 63;
  const int w    = tid >> 6;
  const int wr   = w >> 1;
  const int wc   = w & 1;

  const int N = (int)gridDim.x * 128;
  const long long tile_m = (long long)blockIdx.y * 128;
  const long long tile_n = (long long)blockIdx.x * 128;
  const long long z = blockIdx.z;
  const long long aoff = z * sA + tile_m * (long long)K;
  const long long boff = z * sB + tile_n * (long long)K;

  fx4 acc[4][4];
#pragma unroll
  for (int i = 0; i < 4; i++)
#pragma unroll
    for (int j = 0; j < 4; j++) acc[i][j] = (fx4){0.f, 0.f, 0.f, 0.f};

  const int r_l  = lane >> 2;        // 0..15: row within 16-row stage group
  const int c_l  = (lane & 3) << 3;  // k-chunk for staging
  const int qk   = (lane >> 4) << 3; // fragment k offset
  const int frow = lane & 15;        // fragment row/col

  const size_t sa0 = (size_t)(w * 16 + r_l) * K + c_l;        // stage src offs
  const size_t sa1 = (size_t)(64 + w * 16 + r_l) * K + c_l;
  const int ld0 = (w * 16) * 32;                              // stage dst offs
  const int ld1 = (64 + w * 16) * 32;

  for (int kt = 0; kt < K; kt += 32) {
    __syncthreads();  // previous compute done before overwriting LDS
    {
      const bf16_t* gah = A1 + aoff + kt;
      const bf16_t* gbh = B1 + boff + kt;
      GLDS(gah + sa0, &As[ld0]);
      GLDS(gah + sa1, &As[ld1]);
      GLDS(gbh + sa0, &Bs[ld0]);
      GLDS(gbh + sa1, &Bs[ld1]);
      if (SPLIT) {
        const bf16_t* gal = A2 + aoff + kt;
        const bf16_t* gbl = B2 + boff + kt;
        GLDS(gal + sa0, &As[LO + ld0]);
        GLDS(gal + sa1, &As[LO + ld1]);
        GLDS(gbl + sa0, &Bs[LO + ld0]);
        GLDS(gbl + sa1, &Bs[LO + ld1]);
      }
    }
    __syncthreads();  // barrier drains vmcnt(0): LDS ready

    bf16x8 afh[4], bbh[4];
#pragma unroll
    for (int mi = 0; mi < 4; mi++)
      afh[mi] = *(const bf16x8*)&As[(wr * 64 + mi * 16 + frow) * 32 + qk];
#pragma unroll
    for (int ni = 0; ni < 4; ni++)
      bbh[ni] = *(const bf16x8*)&Bs[(wc * 64 + ni * 16 + frow) * 32 + qk];

    if (!SPLIT) {
#pragma unroll
      for (int mi = 0; mi < 4; mi++)
#pragma unroll
        for (int ni = 0; ni < 4; ni++)
          acc[mi][ni] = __builtin_amdgcn_mfma_f32_16x16x32_bf16(
              afh[mi], bbh[ni], acc[mi][ni], 0, 0, 0);
    } else {
      bf16x8 afl[4], bbl[4];
#pragma unroll
      for (int mi = 0; mi < 4; mi++)
        afl[mi] =
            *(const bf16x8*)&As[LO + (wr * 64 + mi * 16 + frow) * 32 + qk];
#pragma unroll
      for (int ni = 0; ni < 4; ni++)
        bbl[ni] =
            *(const bf16x8*)&Bs[LO + (wc * 64 + ni * 16 + frow) * 32 + qk];
#pragma unroll
      for (int mi = 0; mi < 4; mi++)
#pragma unroll
        for (int ni = 0; ni < 4; ni++) {
          fx4 a = acc[mi][ni];
          a = __builtin_amdgcn_mfma_f32_16x16x32_bf16(afh[mi], bbh[ni], a, 0, 0, 0);
          a = __builtin_amdgcn_mfma_f32_16x16x32_bf16(afl[mi], bbh[ni], a, 0, 0, 0);
          a = __builtin_amdgcn_mfma_f32_16x16x32_bf16(afh[mi], bbl[ni], a, 0, 0, 0);
          acc[mi][ni] = a;
        }
    }
  }

  // Epilogue. C/D layout: col = lane&15, row = (lane>>4)*4 + reg  [m89/m91]
  const int er = (lane >> 4) * 4;
  const int ec = lane & 15;
  const long long crow = tile_m + wr * 64;
  const long long ccol = tile_n + wc * 64;

#pragma unroll
  for (int mi = 0; mi < 4; mi++)
#pragma unroll
    for (int j = 0; j < 4; j++) {
      const long long r = crow + mi * 16 + er + j;
#pragma unroll
      for (int ni = 0; ni < 4; ni++) {
        const long long cc = ccol + ni * 16 + ec;
        const long long idx = z * sC + r * N + cc;
        const float v = acc[mi][ni][j];
        if (EPI == EPI_F32) {
          ((float*)Cv)[idx] = v;
        } else if (EPI == EPI_BF16) {
          ((bf16_t*)Cv)[idx] = (bf16_t)v;
        } else if (EPI == EPI_HILO) {
          const bf16_t h = (bf16_t)v;
          ((bf16_t*)Cv)[idx] = h;
          ((bf16_t*)C2v)[idx] = (bf16_t)(v - (float)h);
        } else {  // EPI_FUSE
          float u = v + bias[cc];
          u = u > 0.f ? u : 0.f;
          ((float*)Cv)[idx] = resid[z * sR + r * N + cc] + u;
        }
      }
    }
}

// ---------------------------------------------------------------------------
// Row softmax over 2048 cols, diagonal mask at (m_base + row-within-batch).
// ---------------------------------------------------------------------------
__global__ __launch_bounds__(256) void softmax_rows(
    const float* __restrict__ s, bf16_t* __restrict__ a, int m_base) {
  __shared__ float red[8];
  const int row = blockIdx.x;
  const int m = m_base + (row & 2047);
  const float* sr = s + (long long)row * 2048;
  bf16_t* ar = a + (long long)row * 2048;

  const int lane = threadIdx.x & 63;
  const int w = threadIdx.x >> 6;

  float v[8];
  float mx = -1e30f;
#pragma unroll
  for (int j = 0; j < 8; j++) {
    const int t = threadIdx.x + j * 256;
    float x = sr[t];
    if (t == m) x = -1e30f;
    v[j] = x;
    mx = fmaxf(mx, x);
  }
  for (int o = 32; o > 0; o >>= 1) mx = fmaxf(mx, __shfl_down(mx, o, 64));
  if (lane == 0) red[w] = mx;
  __syncthreads();
  mx = fmaxf(fmaxf(red[0], red[1]), fmaxf(red[2], red[3]));

  float sum = 0.f;
#pragma unroll
  for (int j = 0; j < 8; j++) {
    const float e = __expf(v[j] - mx);
    v[j] = e;
    sum += e;
  }
  for (int o = 32; o > 0; o >>= 1) sum += __shfl_down(sum, o, 64);
  if (lane == 0) red[4 + w] = sum;
  __syncthreads();
  const float total = red[4] + red[5] + red[6] + red[7];
  const float inv = 1.0f / total;
#pragma unroll
  for (int j = 0; j < 8; j++)
    ar[threadIdx.x + j * 256] = (bf16_t)(v[j] * inv);
}

// ---------------------------------------------------------------------------
// Per-batch transpose: in [8][2048][768] bf16 -> out [8][768][2048] bf16
// ---------------------------------------------------------------------------
__global__ __launch_bounds__(256) void transpose_sd(
    const bf16_t* __restrict__ in, bf16_t* __restrict__ out) {
  __shared__ bf16_t t[32][33];
  const int b = blockIdx.z;
  const int d0 = blockIdx.x * 32;
  const int s0 = blockIdx.y * 32;
  const bf16_t* ib = in + (long long)b * 2048 * 768;
  bf16_t* ob = out + (long long)b * 2048 * 768;
  const int tx = threadIdx.x & 31;
  const int ty = threadIdx.x >> 5;
#pragma unroll
  for (int i = 0; i < 4; i++)
    t[ty + i * 8][tx] = ib[(long long)(s0 + ty + i * 8) * 768 + d0 + tx];
  __syncthreads();
#pragma unroll
  for (int i = 0; i < 4; i++)
    ob[(long long)(d0 + ty + i * 8) * 2048 + s0 + tx] = t[tx][ty + i * 8];
}

// ---------------------------------------------------------------------------
// fp32 -> (hi, lo) bf16 split, 4 elements per thread. x = hi + lo + O(2^-18)
// ---------------------------------------------------------------------------
__global__ __launch_bounds__(256) void split_hilo(
    const float* __restrict__ in, bf16_t* __restrict__ hi,
    bf16_t* __restrict__ lo, int n4) {
  const int i = blockIdx.x * 256 + threadIdx.x;
  if (i >= n4) return;
  const float4 v = ((const float4*)in)[i];
  const bf16_t h0 = (bf16_t)v.x, h1 = (bf16_t)v.y, h2 = (bf16_t)v.z,
               h3 = (bf16_t)v.w;
  ((bf16x4*)hi)[i] = (bf16x4){h0, h1, h2, h3};
  ((bf16x4*)lo)[i] = (bf16x4){(bf16_t)(v.x - (float)h0), (bf16_t)(v.y - (float)h1),
                              (bf16_t)(v.z - (float)h2), (bf16_t)(v.w - (float)h3)};
}

// ---------------------------------------------------------------------------
extern "C" void kernel_launch(void* const* d_in, const int* in_sizes, int n_in,
                              void* d_out, int out_size, void* d_ws,
                              size_t ws_size, hipStream_t stream) {
  const float* x  = (const float*)d_in[0];
  const float* W  = (const float*)d_in[1];
  const float* pw = (const float*)d_in[2];
  const float* pb = (const float*)d_in[3];

  const long long S = 2048, D = 768;
  const long long BS = 8 * S;  // 16384 rows

  // ---- fixed workspace (~81 MB) ----
  char* p = (char*)d_ws;
  auto carve = [&](long long bytes) {
    char* q = p;
    p += (bytes + 255) & ~255LL;
    return q;
  };
  bf16_t* xh = (bf16_t*)carve(BS * D * 2);  // x hi          25.2 MB
  bf16_t* xl = (bf16_t*)carve(BS * D * 2);  // x lo          25.2 MB
  bf16_t* xT = (bf16_t*)carve(BS * D * 2);  // x^T (hi)      25.2 MB
  bf16_t* Wh = (bf16_t*)carve(D * D * 2);   // W hi           1.2 MB
  bf16_t* Wl = (bf16_t*)carve(D * D * 2);   // W lo           1.2 MB
  bf16_t* ph = (bf16_t*)carve(D * D * 2);   // proj_w hi      1.2 MB
  bf16_t* pl = (bf16_t*)carve(D * D * 2);   // proj_w lo (split writes both)
  const long long avail = (long long)ws_size - (long long)(p - (char*)d_ws);

  // ---- input splits + transpose ----
  split_hilo<<<(unsigned)(BS * D / 4 / 256), 256, 0, stream>>>(
      x, xh, xl, (int)(BS * D / 4));
  split_hilo<<<(unsigned)(D * D / 4 / 256), 256, 0, stream>>>(
      W, Wh, Wl, (int)(D * D / 4));
  split_hilo<<<(unsigned)(D * D / 4 / 256), 256, 0, stream>>>(
      pw, ph, pl, (int)(D * D / 4));
  transpose_sd<<<dim3(24, 64, 8), 256, 0, stream>>>(xh, xT);

  // per-batch chunk footprint: Wx hi+lo, s fp32, a bf16 (c aliases Wx_hi)
  const long long perb = 2 * S * D * 2 + S * S * 4 + S * S * 2;  // 30 MiB

  if (avail >= perb) {
    // ---- batch-chunk mode: nb batches at a time via blockIdx.z ----
    int nb = (int)(avail / perb);
    if (nb > 8) nb = 8;
    char* q = p;
    bf16_t* Wxh = (bf16_t*)q; q += (long long)nb * S * D * 2;
    bf16_t* Wxl = (bf16_t*)q; q += (long long)nb * S * D * 2;
    float*  sb  = (float*)q;  q += (long long)nb * S * S * 4;
    bf16_t* ab  = (bf16_t*)q;
    bf16_t* cc  = Wxh;  // c aliases Wx_hi (dead after GEMM2 of same chunk)

    for (int c0 = 0; c0 < 8; c0 += nb) {
      const int n = (8 - c0) < nb ? (8 - c0) : nb;
      // GEMM1: Wx = x @ W^T (fused split, hi/lo out)
      gemm_bt<true, EPI_HILO><<<dim3(6, 16, n), 256, 0, stream>>>(
          xh + (long long)c0 * S * D, xl + (long long)c0 * S * D, Wh, Wl,
          Wxh, Wxl, 768, S * D, 0, S * D, nullptr, nullptr, 0);
      // GEMM2: s = Wx @ x^T per batch (fused split, fp32 out)
      gemm_bt<true, EPI_F32><<<dim3(16, 16, n), 256, 0, stream>>>(
          Wxh, Wxl, xh + (long long)c0 * S * D, xl + (long long)c0 * S * D,
          sb, nullptr, 768, S * D, S * D, S * S, nullptr, nullptr, 0);
      softmax_rows<<<(unsigned)(n * S), 256, 0, stream>>>(sb, ab, 0);
      // GEMM3: c = a @ x (bf16 out)
      gemm_bt<false, EPI_BF16><<<dim3(6, 16, n), 256, 0, stream>>>(
          ab, nullptr, xT + (long long)c0 * D * S, nullptr, cc, nullptr, 2048,
          S * S, D * S, S * D, nullptr, nullptr, 0);
      // GEMM4: out = x + relu(c @ proj_w^T + pb)
      gemm_bt<false, EPI_FUSE><<<dim3(6, 16, n), 256, 0, stream>>>(
          cc, nullptr, ph, nullptr, (float*)d_out + (long long)c0 * S * D,
          nullptr, 768, S * D, 0, S * D, pb, x + (long long)c0 * S * D, S * D);
    }
  } else {
    // ---- row-chunk mode: R rows (multiple of 128) within one batch ----
    long long R = (avail / 15360) & ~127LL;
    if (R < 128) R = 128;
    if (R > 2048) R = 2048;
    char* q = p;
    bf16_t* Wxh = (bf16_t*)q; q += R * D * 2;
    bf16_t* Wxl = (bf16_t*)q; q += R * D * 2;
    float*  sb  = (float*)q;  q += R * S * 4;
    bf16_t* ab  = (bf16_t*)q;
    bf16_t* cc  = Wxh;

    for (int b = 0; b < 8; b++) {
      for (long long r0 = 0; r0 < S; r0 += R) {
        const long long rows = (S - r0) < R ? (S - r0) : R;
        const unsigned gy = (unsigned)(rows / 128);
        gemm_bt<true, EPI_HILO><<<dim3(6, gy, 1), 256, 0, stream>>>(
            xh + ((long long)b * S + r0) * D, xl + ((long long)b * S + r0) * D,
            Wh, Wl, Wxh, Wxl, 768, 0, 0, 0, nullptr, nullptr, 0);
        gemm_bt<true, EPI_F32><<<dim3(16, gy, 1), 256, 0, stream>>>(
            Wxh, Wxl, xh + (long long)b * S * D, xl + (long long)b * S * D,
            sb, nullptr, 768, 0, 0, 0, nullptr, nullptr, 0);
        softmax_rows<<<(unsigned)rows, 256, 0, stream>>>(sb, ab, (int)r0);
        gemm_bt<false, EPI_BF16><<<dim3(6, gy, 1), 256, 0, stream>>>(
            ab, nullptr, xT + (long long)b * D * S, nullptr, cc, nullptr, 2048,
            0, 0, 0, nullptr, nullptr, 0);
        gemm_bt<false, EPI_FUSE><<<dim3(6, gy, 1), 256, 0, stream>>>(
            cc, nullptr, ph, nullptr,
            (float*)d_out + ((long long)b * S + r0) * D, nullptr, 768,
            0, 0, 0, pb, x + ((long long)b * S + r0) * D, 0);
      }
    }
  }
}

// Round 5
// 543.463 us; speedup vs baseline: 1.2328x; 1.1012x over previous
//
#include <hip/hip_runtime.h>
#include <hip/hip_bf16.h>

typedef _Float16 fp16_t;
typedef __attribute__((ext_vector_type(8))) _Float16 fp16x8;
typedef __attribute__((ext_vector_type(4))) _Float16 fp16x4;
typedef __attribute__((ext_vector_type(4))) float fx4;

#define GLDS(g, l)                                                              \
  __builtin_amdgcn_global_load_lds(                                             \
      (const __attribute__((address_space(1))) void*)(g),                       \
      (__attribute__((address_space(3))) void*)(l), 16, 0, 0)

enum { EPI_F32 = 0, EPI_F16 = 1, EPI_HILO = 2, EPI_FUSE = 3 };

// ---------------------------------------------------------------------------
// BT-layout fp16 GEMM with optional hi/lo split on either operand:
//   terms = Ah·Bh  (+ Al·Bh if ASPLIT)  (+ Ah·Bl if BSPLIT)
// fp16 split: hi+lo captures ~21 mantissa bits (~fp32). Dropped lo·lo and
// (if !BSPLIT) Ah·Bl terms are O(2^-11) relative each.
// A: [M,K] row-major, B: [N,K] row-major. Tile 128x128, BK=32, 4 waves.
// Staging via global_load_lds width=16. 16/32/48 MFMA per barrier pair.
// ---------------------------------------------------------------------------
template <bool ASPLIT, bool BSPLIT, int EPI>
__global__ __launch_bounds__(256) void gemm_bt(
    const fp16_t* __restrict__ A1, const fp16_t* __restrict__ A2,
    const fp16_t* __restrict__ B1, const fp16_t* __restrict__ B2,
    void* __restrict__ Cv, void* __restrict__ C2v, int K,
    long long sA, long long sB, long long sC,
    const float* __restrict__ bias, const float* __restrict__ resid,
    long long sR) {
  constexpr int ALO = ASPLIT ? 128 * 32 : 0;
  constexpr int BLO = BSPLIT ? 128 * 32 : 0;
  __shared__ __align__(16) fp16_t As[128 * 32 + ALO];
  __shared__ __align__(16) fp16_t Bs[128 * 32 + BLO];

  const int tid  = threadIdx.x;
  const int lane = tid & 63;
  const int w    = tid >> 6;
  const int wr   = w >> 1;
  const int wc   = w & 1;

  const int N = (int)gridDim.x * 128;
  const long long tile_m = (long long)blockIdx.y * 128;
  const long long tile_n = (long long)blockIdx.x * 128;
  const long long z = blockIdx.z;
  const long long aoff = z * sA + tile_m * (long long)K;
  const long long boff = z * sB + tile_n * (long long)K;

  fx4 acc[4][4];
#pragma unroll
  for (int i = 0; i < 4; i++)
#pragma unroll
    for (int j = 0; j < 4; j++) acc[i][j] = (fx4){0.f, 0.f, 0.f, 0.f};

  const int r_l  = lane >> 2;        // 0..15: row within 16-row stage group
  const int c_l  = (lane & 3) << 3;  // k-chunk for staging
  const int qk   = (lane >> 4) << 3; // fragment k offset
  const int frow = lane & 15;        // fragment row/col

  const size_t sa0 = (size_t)(w * 16 + r_l) * K + c_l;
  const size_t sa1 = (size_t)(64 + w * 16 + r_l) * K + c_l;
  const int ld0 = (w * 16) * 32;
  const int ld1 = (64 + w * 16) * 32;

  for (int kt = 0; kt < K; kt += 32) {
    __syncthreads();  // previous compute done before overwriting LDS
    {
      const fp16_t* gah = A1 + aoff + kt;
      const fp16_t* gbh = B1 + boff + kt;
      GLDS(gah + sa0, &As[ld0]);
      GLDS(gah + sa1, &As[ld1]);
      GLDS(gbh + sa0, &Bs[ld0]);
      GLDS(gbh + sa1, &Bs[ld1]);
      if (ASPLIT) {
        const fp16_t* gal = A2 + aoff + kt;
        GLDS(gal + sa0, &As[ALO + ld0]);
        GLDS(gal + sa1, &As[ALO + ld1]);
      }
      if (BSPLIT) {
        const fp16_t* gbl = B2 + boff + kt;
        GLDS(gbl + sa0, &Bs[BLO + ld0]);
        GLDS(gbl + sa1, &Bs[BLO + ld1]);
      }
    }
    __syncthreads();  // barrier drains vmcnt(0): LDS ready

    fp16x8 afh[4], bbh[4];
#pragma unroll
    for (int mi = 0; mi < 4; mi++)
      afh[mi] = *(const fp16x8*)&As[(wr * 64 + mi * 16 + frow) * 32 + qk];
#pragma unroll
    for (int ni = 0; ni < 4; ni++)
      bbh[ni] = *(const fp16x8*)&Bs[(wc * 64 + ni * 16 + frow) * 32 + qk];

    fp16x8 afl[4], bbl[4];
    if (ASPLIT) {
#pragma unroll
      for (int mi = 0; mi < 4; mi++)
        afl[mi] =
            *(const fp16x8*)&As[ALO + (wr * 64 + mi * 16 + frow) * 32 + qk];
    }
    if (BSPLIT) {
#pragma unroll
      for (int ni = 0; ni < 4; ni++)
        bbl[ni] =
            *(const fp16x8*)&Bs[BLO + (wc * 64 + ni * 16 + frow) * 32 + qk];
    }

#pragma unroll
    for (int mi = 0; mi < 4; mi++)
#pragma unroll
      for (int ni = 0; ni < 4; ni++) {
        fx4 a = acc[mi][ni];
        a = __builtin_amdgcn_mfma_f32_16x16x32_f16(afh[mi], bbh[ni], a, 0, 0, 0);
        if (ASPLIT)
          a = __builtin_amdgcn_mfma_f32_16x16x32_f16(afl[mi], bbh[ni], a, 0, 0, 0);
        if (BSPLIT)
          a = __builtin_amdgcn_mfma_f32_16x16x32_f16(afh[mi], bbl[ni], a, 0, 0, 0);
        acc[mi][ni] = a;
      }
  }

  // Epilogue. C/D layout: col = lane&15, row = (lane>>4)*4 + reg  [m89/m91]
  const int er = (lane >> 4) * 4;
  const int ec = lane & 15;
  const long long crow = tile_m + wr * 64;
  const long long ccol = tile_n + wc * 64;

#pragma unroll
  for (int mi = 0; mi < 4; mi++)
#pragma unroll
    for (int j = 0; j < 4; j++) {
      const long long r = crow + mi * 16 + er + j;
#pragma unroll
      for (int ni = 0; ni < 4; ni++) {
        const long long cc = ccol + ni * 16 + ec;
        const long long idx = z * sC + r * N + cc;
        const float v = acc[mi][ni][j];
        if (EPI == EPI_F32) {
          ((float*)Cv)[idx] = v;
        } else if (EPI == EPI_F16) {
          ((fp16_t*)Cv)[idx] = (fp16_t)v;
        } else if (EPI == EPI_HILO) {
          const fp16_t h = (fp16_t)v;
          ((fp16_t*)Cv)[idx] = h;
          ((fp16_t*)C2v)[idx] = (fp16_t)(v - (float)h);
        } else {  // EPI_FUSE
          float u = v + bias[cc];
          u = u > 0.f ? u : 0.f;
          ((float*)Cv)[idx] = resid[z * sR + r * N + cc] + u;
        }
      }
    }
}

// ---------------------------------------------------------------------------
// Row softmax over 2048 cols, diagonal mask at (m_base + row-within-batch).
// Vectorized: float4 loads, fp16x8 store. One 256-thread block per row.
// ---------------------------------------------------------------------------
__global__ __launch_bounds__(256) void softmax_rows(
    const float* __restrict__ s, fp16_t* __restrict__ a, int m_base) {
  __shared__ float red[8];
  const int row = blockIdx.x;
  const int m = m_base + (row & 2047);
  const float4* sr = (const float4*)(s + (long long)row * 2048);
  fp16x8* ar = (fp16x8*)(a + (long long)row * 2048);

  const int lane = threadIdx.x & 63;
  const int w = threadIdx.x >> 6;
  const int t0 = threadIdx.x * 8;

  const float4 u0 = sr[threadIdx.x * 2];
  const float4 u1 = sr[threadIdx.x * 2 + 1];
  float v[8] = {u0.x, u0.y, u0.z, u0.w, u1.x, u1.y, u1.z, u1.w};

  float mx = -1e30f;
#pragma unroll
  for (int j = 0; j < 8; j++) {
    if (t0 + j == m) v[j] = -1e30f;  // diagonal mask
    mx = fmaxf(mx, v[j]);
  }
  for (int o = 32; o > 0; o >>= 1) mx = fmaxf(mx, __shfl_down(mx, o, 64));
  if (lane == 0) red[w] = mx;
  __syncthreads();
  mx = fmaxf(fmaxf(red[0], red[1]), fmaxf(red[2], red[3]));

  float sum = 0.f;
#pragma unroll
  for (int j = 0; j < 8; j++) {
    const float e = __expf(v[j] - mx);
    v[j] = e;
    sum += e;
  }
  for (int o = 32; o > 0; o >>= 1) sum += __shfl_down(sum, o, 64);
  if (lane == 0) red[4 + w] = sum;
  __syncthreads();
  const float total = red[4] + red[5] + red[6] + red[7];
  const float inv = 1.0f / total;

  fp16x8 o;
#pragma unroll
  for (int j = 0; j < 8; j++) o[j] = (fp16_t)(v[j] * inv);
  ar[threadIdx.x] = o;
}

// ---------------------------------------------------------------------------
// Per-batch transpose: in [8][2048][768] fp16 -> out [8][768][2048] fp16
// ---------------------------------------------------------------------------
__global__ __launch_bounds__(256) void transpose_sd(
    const fp16_t* __restrict__ in, fp16_t* __restrict__ out) {
  __shared__ fp16_t t[32][33];
  const int b = blockIdx.z;
  const int d0 = blockIdx.x * 32;
  const int s0 = blockIdx.y * 32;
  const fp16_t* ib = in + (long long)b * 2048 * 768;
  fp16_t* ob = out + (long long)b * 2048 * 768;
  const int tx = threadIdx.x & 31;
  const int ty = threadIdx.x >> 5;
#pragma unroll
  for (int i = 0; i < 4; i++)
    t[ty + i * 8][tx] = ib[(long long)(s0 + ty + i * 8) * 768 + d0 + tx];
  __syncthreads();
#pragma unroll
  for (int i = 0; i < 4; i++)
    ob[(long long)(d0 + ty + i * 8) * 2048 + s0 + tx] = t[tx][ty + i * 8];
}

// ---------------------------------------------------------------------------
// fp32 -> (hi, lo) fp16 split, 4 elements per thread. x = hi + lo + O(2^-21)
// ---------------------------------------------------------------------------
__global__ __launch_bounds__(256) void split_hilo(
    const float* __restrict__ in, fp16_t* __restrict__ hi,
    fp16_t* __restrict__ lo, int n4) {
  const int i = blockIdx.x * 256 + threadIdx.x;
  if (i >= n4) return;
  const float4 v = ((const float4*)in)[i];
  const fp16_t h0 = (fp16_t)v.x, h1 = (fp16_t)v.y, h2 = (fp16_t)v.z,
               h3 = (fp16_t)v.w;
  ((fp16x4*)hi)[i] = (fp16x4){h0, h1, h2, h3};
  ((fp16x4*)lo)[i] =
      (fp16x4){(fp16_t)(v.x - (float)h0), (fp16_t)(v.y - (float)h1),
               (fp16_t)(v.z - (float)h2), (fp16_t)(v.w - (float)h3)};
}

// ---------------------------------------------------------------------------
extern "C" void kernel_launch(void* const* d_in, const int* in_sizes, int n_in,
                              void* d_out, int out_size, void* d_ws,
                              size_t ws_size, hipStream_t stream) {
  const float* x  = (const float*)d_in[0];
  const float* W  = (const float*)d_in[1];
  const float* pw = (const float*)d_in[2];
  const float* pb = (const float*)d_in[3];

  const long long S = 2048, D = 768;
  const long long BS = 8 * S;  // 16384 rows

  // ---- fixed workspace (~130 MB) ----
  char* p = (char*)d_ws;
  auto carve = [&](long long bytes) {
    char* q = p;
    p += (bytes + 255) & ~255LL;
    return q;
  };
  fp16_t* xh  = (fp16_t*)carve(BS * D * 2);  // x hi            25.2 MB
  fp16_t* xl  = (fp16_t*)carve(BS * D * 2);  // x lo (G1 only)  25.2 MB
  fp16_t* xT  = (fp16_t*)carve(BS * D * 2);  // x^T (hi)        25.2 MB
  fp16_t* Wxh = (fp16_t*)carve(BS * D * 2);  // Wx hi / c       25.2 MB
  fp16_t* Wxl = (fp16_t*)carve(BS * D * 2);  // Wx lo           25.2 MB
  fp16_t* Wh  = (fp16_t*)carve(D * D * 2);   // W hi             1.2 MB
  fp16_t* Wl  = (fp16_t*)carve(D * D * 2);   // W lo             1.2 MB
  fp16_t* ph  = (fp16_t*)carve(D * D * 2);   // proj_w hi        1.2 MB
  fp16_t* pl  = (fp16_t*)carve(D * D * 2);   // proj_w lo (unused)
  fp16_t* cb  = Wxh;  // c aliases Wx hi: Wx[batch] dead after GEMM2[batch]
  const long long avail = (long long)ws_size - (long long)(p - (char*)d_ws);

  // ---- input splits + transpose ----
  split_hilo<<<(unsigned)(BS * D / 4 / 256), 256, 0, stream>>>(
      x, xh, xl, (int)(BS * D / 4));
  split_hilo<<<(unsigned)(D * D / 4 / 256), 256, 0, stream>>>(
      W, Wh, Wl, (int)(D * D / 4));
  split_hilo<<<(unsigned)(D * D / 4 / 256), 256, 0, stream>>>(
      pw, ph, pl, (int)(D * D / 4));
  transpose_sd<<<dim3(24, 64, 8), 256, 0, stream>>>(xh, xT);

  // GEMM1 (full, 3-term): Wx = x @ W^T, hi/lo out.  768 blocks = 3/CU.
  gemm_bt<true, true, EPI_HILO><<<dim3(6, 128, 1), 256, 0, stream>>>(
      xh, xl, Wh, Wl, Wxh, Wxl, 768, 0, 0, 0, nullptr, nullptr, 0);

  // ---- attention middle: GEMM2 -> softmax -> GEMM3, chunked to fit ws ----
  const long long perb = S * S * 4 + S * S * 2;  // s fp32 + a fp16 per batch

  if (avail >= perb) {
    int nb = (int)(avail / perb);
    if (nb > 8) nb = 8;
    char* q = p;
    float*  sb = (float*)q; q += (long long)nb * S * S * 4;
    fp16_t* ab = (fp16_t*)q;

    for (int c0 = 0; c0 < 8; c0 += nb) {
      const int n = (8 - c0) < nb ? (8 - c0) : nb;
      // GEMM2 (2-term): s = (Wx_hi + Wx_lo) @ x_hi^T per batch, fp32 out
      gemm_bt<true, false, EPI_F32><<<dim3(16, 16, n), 256, 0, stream>>>(
          Wxh + (long long)c0 * S * D, Wxl + (long long)c0 * S * D,
          xh + (long long)c0 * S * D, nullptr, sb, nullptr, 768,
          S * D, S * D, S * S, nullptr, nullptr, 0);
      softmax_rows<<<(unsigned)(n * S), 256, 0, stream>>>(sb, ab, 0);
      // GEMM3: c = a @ x  (fp16 out, aliases Wx hi)
      gemm_bt<false, false, EPI_F16><<<dim3(6, 16, n), 256, 0, stream>>>(
          ab, nullptr, xT + (long long)c0 * D * S, nullptr,
          cb + (long long)c0 * S * D, nullptr, 2048,
          S * S, D * S, S * D, nullptr, nullptr, 0);
    }
  } else {
    // row-chunk fallback: R rows (multiple of 128) within one batch
    long long R = (avail / 12288) & ~127LL;  // 8192 B (s) + 4096 B (a) per row
    if (R < 128) R = 128;
    if (R > 2048) R = 2048;
    char* q = p;
    float*  sb = (float*)q; q += R * S * 4;
    fp16_t* ab = (fp16_t*)q;
    for (int b = 0; b < 8; b++) {
      for (long long r0 = 0; r0 < S; r0 += R) {
        const long long rows = (S - r0) < R ? (S - r0) : R;
        const unsigned gy = (unsigned)(rows / 128);
        gemm_bt<true, false, EPI_F32><<<dim3(16, gy, 1), 256, 0, stream>>>(
            Wxh + ((long long)b * S + r0) * D, Wxl + ((long long)b * S + r0) * D,
            xh + (long long)b * S * D, nullptr, sb, nullptr, 768,
            0, 0, 0, nullptr, nullptr, 0);
        softmax_rows<<<(unsigned)rows, 256, 0, stream>>>(sb, ab, (int)r0);
        gemm_bt<false, false, EPI_F16><<<dim3(6, gy, 1), 256, 0, stream>>>(
            ab, nullptr, xT + (long long)b * D * S, nullptr,
            cb + ((long long)b * S + r0) * D, nullptr, 2048,
            0, 0, 0, nullptr, nullptr, 0);
      }
    }
  }

  // GEMM4 (full): out = x + relu(c @ proj_w^T + pb).  768 blocks = 3/CU.
  gemm_bt<false, false, EPI_FUSE><<<dim3(6, 128, 1), 256, 0, stream>>>(
      cb, nullptr, ph, nullptr, (float*)d_out, nullptr, 768,
      0, 0, 0, pb, x, 0);
}

// Round 6
// 496.276 us; speedup vs baseline: 1.3500x; 1.0951x over previous
//
#include <hip/hip_runtime.h>
#include <hip/hip_bf16.h>

typedef _Float16 fp16_t;
typedef __attribute__((ext_vector_type(8))) _Float16 fp16x8;
typedef __attribute__((ext_vector_type(4))) _Float16 fp16x4;
typedef __attribute__((ext_vector_type(4))) float fx4;

#define GLDS(g, l)                                                              \
  __builtin_amdgcn_global_load_lds(                                             \
      (const __attribute__((address_space(1))) void*)(g),                       \
      (__attribute__((address_space(3))) void*)(l), 16, 0, 0)

enum { EPI_F32 = 0, EPI_F16 = 1, EPI_FUSE = 2 };

// ---------------------------------------------------------------------------
// BT-layout fp16 GEMM: C = A1·B1^T (+ A2·B1^T if ASPLIT, + A1·B2^T if BSPLIT)
// A: [M,K] row-major, B: [N,K] row-major. Tile 128x128, BK=32, 4 waves.
// Staging via global_load_lds width=16 with a BANK-CONFLICT SWIZZLE:
//   rows are 64 B wide -> naive 16-row b128 fragment reads hit banks {0,16}
//   (8-way). GLDS forbids LDS padding (wave-uniform base + lane*16), so we
//   permute the 16B chunks at the GLOBAL source: lane (r,m) fetches global
//   chunk g=(m+(r>>1))&3; reads invert with slot=(q-(frow>>1))&3. Rows then
//   spread over all 8 bank groups (2-way residual = free, m136).
// ---------------------------------------------------------------------------
template <bool ASPLIT, bool BSPLIT, int EPI>
__global__ __launch_bounds__(256) void gemm_bt(
    const fp16_t* __restrict__ A1, const fp16_t* __restrict__ A2,
    const fp16_t* __restrict__ B1, const fp16_t* __restrict__ B2,
    void* __restrict__ Cv, int K,
    long long sA, long long sB, long long sC,
    const float* __restrict__ bias, const float* __restrict__ resid,
    long long sR) {
  constexpr int ALO = ASPLIT ? 128 * 32 : 0;
  constexpr int BLO = BSPLIT ? 128 * 32 : 0;
  __shared__ __align__(16) fp16_t As[128 * 32 + ALO];
  __shared__ __align__(16) fp16_t Bs[128 * 32 + BLO];

  const int tid  = threadIdx.x;
  const int lane = tid & 63;
  const int w    = tid >> 6;
  const int wr   = w >> 1;
  const int wc   = w & 1;

  const int N = (int)gridDim.x * 128;
  const long long tile_m = (long long)blockIdx.y * 128;
  const long long tile_n = (long long)blockIdx.x * 128;
  const long long z = blockIdx.z;
  const long long aoff = z * sA + tile_m * (long long)K;
  const long long boff = z * sB + tile_n * (long long)K;

  fx4 acc[4][4];
#pragma unroll
  for (int i = 0; i < 4; i++)
#pragma unroll
    for (int j = 0; j < 4; j++) acc[i][j] = (fx4){0.f, 0.f, 0.f, 0.f};

  // staging: lane -> (row r_l, LDS slot m); fetch global chunk (m+(r>>1))&3
  const int r_l = lane >> 2;
  const int c_l = ((((lane & 3) + ((r_l >> 1) & 3)) & 3) << 3);
  // fragment read: global chunk q=(lane>>4) lives at swizzled slot
  const int frow = lane & 15;
  const int qoff = (((lane >> 4) - ((frow >> 1) & 3)) & 3) << 3;

  const size_t sa0 = (size_t)(w * 16 + r_l) * K + c_l;
  const size_t sa1 = (size_t)(64 + w * 16 + r_l) * K + c_l;
  const int ld0 = (w * 16) * 32;
  const int ld1 = (64 + w * 16) * 32;

  for (int kt = 0; kt < K; kt += 32) {
    __syncthreads();  // previous compute done before overwriting LDS
    {
      const fp16_t* gah = A1 + aoff + kt;
      const fp16_t* gbh = B1 + boff + kt;
      GLDS(gah + sa0, &As[ld0]);
      GLDS(gah + sa1, &As[ld1]);
      GLDS(gbh + sa0, &Bs[ld0]);
      GLDS(gbh + sa1, &Bs[ld1]);
      if (ASPLIT) {
        const fp16_t* gal = A2 + aoff + kt;
        GLDS(gal + sa0, &As[ALO + ld0]);
        GLDS(gal + sa1, &As[ALO + ld1]);
      }
      if (BSPLIT) {
        const fp16_t* gbl = B2 + boff + kt;
        GLDS(gbl + sa0, &Bs[BLO + ld0]);
        GLDS(gbl + sa1, &Bs[BLO + ld1]);
      }
    }
    __syncthreads();  // barrier drains vmcnt(0): LDS ready

    fp16x8 afh[4], bbh[4];
#pragma unroll
    for (int mi = 0; mi < 4; mi++)
      afh[mi] = *(const fp16x8*)&As[(wr * 64 + mi * 16 + frow) * 32 + qoff];
#pragma unroll
    for (int ni = 0; ni < 4; ni++)
      bbh[ni] = *(const fp16x8*)&Bs[(wc * 64 + ni * 16 + frow) * 32 + qoff];

    fp16x8 afl[4], bbl[4];
    if (ASPLIT) {
#pragma unroll
      for (int mi = 0; mi < 4; mi++)
        afl[mi] =
            *(const fp16x8*)&As[ALO + (wr * 64 + mi * 16 + frow) * 32 + qoff];
    }
    if (BSPLIT) {
#pragma unroll
      for (int ni = 0; ni < 4; ni++)
        bbl[ni] =
            *(const fp16x8*)&Bs[BLO + (wc * 64 + ni * 16 + frow) * 32 + qoff];
    }

#pragma unroll
    for (int mi = 0; mi < 4; mi++)
#pragma unroll
      for (int ni = 0; ni < 4; ni++) {
        fx4 a = acc[mi][ni];
        a = __builtin_amdgcn_mfma_f32_16x16x32_f16(afh[mi], bbh[ni], a, 0, 0, 0);
        if (ASPLIT)
          a = __builtin_amdgcn_mfma_f32_16x16x32_f16(afl[mi], bbh[ni], a, 0, 0, 0);
        if (BSPLIT)
          a = __builtin_amdgcn_mfma_f32_16x16x32_f16(afh[mi], bbl[ni], a, 0, 0, 0);
        acc[mi][ni] = a;
      }
  }

  // Epilogue. C/D layout: col = lane&15, row = (lane>>4)*4 + reg  [m89/m91]
  const int er = (lane >> 4) * 4;
  const int ec = lane & 15;
  const long long crow = tile_m + wr * 64;
  const long long ccol = tile_n + wc * 64;

#pragma unroll
  for (int mi = 0; mi < 4; mi++)
#pragma unroll
    for (int j = 0; j < 4; j++) {
      const long long r = crow + mi * 16 + er + j;
#pragma unroll
      for (int ni = 0; ni < 4; ni++) {
        const long long cc = ccol + ni * 16 + ec;
        const long long idx = z * sC + r * N + cc;
        const float v = acc[mi][ni][j];
        if (EPI == EPI_F32) {
          ((float*)Cv)[idx] = v;
        } else if (EPI == EPI_F16) {
          ((fp16_t*)Cv)[idx] = (fp16_t)v;
        } else {  // EPI_FUSE
          float u = v + bias[cc];
          u = u > 0.f ? u : 0.f;
          ((float*)Cv)[idx] = resid[z * sR + r * N + cc] + u;
        }
      }
    }
}

// ---------------------------------------------------------------------------
// Row softmax over 2048 cols, diagonal mask at (m_base + row-within-batch).
// Vectorized: float4 loads, fp16x8 store. One 256-thread block per row.
// ---------------------------------------------------------------------------
__global__ __launch_bounds__(256) void softmax_rows(
    const float* __restrict__ s, fp16_t* __restrict__ a, int m_base) {
  __shared__ float red[8];
  const int row = blockIdx.x;
  const int m = m_base + (row & 2047);
  const float4* sr = (const float4*)(s + (long long)row * 2048);
  fp16x8* ar = (fp16x8*)(a + (long long)row * 2048);

  const int lane = threadIdx.x & 63;
  const int w = threadIdx.x >> 6;
  const int t0 = threadIdx.x * 8;

  const float4 u0 = sr[threadIdx.x * 2];
  const float4 u1 = sr[threadIdx.x * 2 + 1];
  float v[8] = {u0.x, u0.y, u0.z, u0.w, u1.x, u1.y, u1.z, u1.w};

  float mx = -1e30f;
#pragma unroll
  for (int j = 0; j < 8; j++) {
    if (t0 + j == m) v[j] = -1e30f;  // diagonal mask
    mx = fmaxf(mx, v[j]);
  }
  for (int o = 32; o > 0; o >>= 1) mx = fmaxf(mx, __shfl_down(mx, o, 64));
  if (lane == 0) red[w] = mx;
  __syncthreads();
  mx = fmaxf(fmaxf(red[0], red[1]), fmaxf(red[2], red[3]));

  float sum = 0.f;
#pragma unroll
  for (int j = 0; j < 8; j++) {
    const float e = __expf(v[j] - mx);
    v[j] = e;
    sum += e;
  }
  for (int o = 32; o > 0; o >>= 1) sum += __shfl_down(sum, o, 64);
  if (lane == 0) red[4 + w] = sum;
  __syncthreads();
  const float total = red[4] + red[5] + red[6] + red[7];
  const float inv = 1.0f / total;

  fp16x8 o;
#pragma unroll
  for (int j = 0; j < 8; j++) o[j] = (fp16_t)(v[j] * inv);
  ar[threadIdx.x] = o;
}

// ---------------------------------------------------------------------------
// Per-batch transpose: in [8][2048][768] fp16 -> out [8][768][2048] fp16
// ---------------------------------------------------------------------------
__global__ __launch_bounds__(256) void transpose_sd(
    const fp16_t* __restrict__ in, fp16_t* __restrict__ out) {
  __shared__ fp16_t t[32][33];
  const int b = blockIdx.z;
  const int d0 = blockIdx.x * 32;
  const int s0 = blockIdx.y * 32;
  const fp16_t* ib = in + (long long)b * 2048 * 768;
  fp16_t* ob = out + (long long)b * 2048 * 768;
  const int tx = threadIdx.x & 31;
  const int ty = threadIdx.x >> 5;
#pragma unroll
  for (int i = 0; i < 4; i++)
    t[ty + i * 8][tx] = ib[(long long)(s0 + ty + i * 8) * 768 + d0 + tx];
  __syncthreads();
#pragma unroll
  for (int i = 0; i < 4; i++)
    ob[(long long)(d0 + ty + i * 8) * 2048 + s0 + tx] = t[tx][ty + i * 8];
}

// ---------------------------------------------------------------------------
// fp32 -> (hi, lo) fp16 split, 4 elements per thread. x = hi + lo + O(2^-21)
// ---------------------------------------------------------------------------
__global__ __launch_bounds__(256) void split_hilo(
    const float* __restrict__ in, fp16_t* __restrict__ hi,
    fp16_t* __restrict__ lo, int n4) {
  const int i = blockIdx.x * 256 + threadIdx.x;
  if (i >= n4) return;
  const float4 v = ((const float4*)in)[i];
  const fp16_t h0 = (fp16_t)v.x, h1 = (fp16_t)v.y, h2 = (fp16_t)v.z,
               h3 = (fp16_t)v.w;
  ((fp16x4*)hi)[i] = (fp16x4){h0, h1, h2, h3};
  ((fp16x4*)lo)[i] =
      (fp16x4){(fp16_t)(v.x - (float)h0), (fp16_t)(v.y - (float)h1),
               (fp16_t)(v.z - (float)h2), (fp16_t)(v.w - (float)h3)};
}

// ---------------------------------------------------------------------------
// fp32 -> fp16 cast, 4 elements per thread
// ---------------------------------------------------------------------------
__global__ __launch_bounds__(256) void cast_f32_f16(
    const float* __restrict__ in, fp16_t* __restrict__ out, int n4) {
  const int i = blockIdx.x * 256 + threadIdx.x;
  if (i >= n4) return;
  const float4 v = ((const float4*)in)[i];
  ((fp16x4*)out)[i] =
      (fp16x4){(fp16_t)v.x, (fp16_t)v.y, (fp16_t)v.z, (fp16_t)v.w};
}

// ---------------------------------------------------------------------------
extern "C" void kernel_launch(void* const* d_in, const int* in_sizes, int n_in,
                              void* d_out, int out_size, void* d_ws,
                              size_t ws_size, hipStream_t stream) {
  const float* x  = (const float*)d_in[0];
  const float* W  = (const float*)d_in[1];
  const float* pw = (const float*)d_in[2];
  const float* pb = (const float*)d_in[3];

  const long long S = 2048, D = 768;
  const long long BS = 8 * S;  // 16384 rows

  // ---- fixed workspace (~103 MB) ----
  char* p = (char*)d_ws;
  auto carve = [&](long long bytes) {
    char* q = p;
    p += (bytes + 255) & ~255LL;
    return q;
  };
  fp16_t* xh = (fp16_t*)carve(BS * D * 2);  // x hi            25.2 MB
  fp16_t* xl = (fp16_t*)carve(BS * D * 2);  // x lo (G1 only)  25.2 MB
  fp16_t* xT = (fp16_t*)carve(BS * D * 2);  // x^T (hi)        25.2 MB
  fp16_t* Wx = (fp16_t*)carve(BS * D * 2);  // Wx fp16 / c     25.2 MB
  fp16_t* Wh = (fp16_t*)carve(D * D * 2);   // W fp16           1.2 MB
  fp16_t* ph = (fp16_t*)carve(D * D * 2);   // proj_w fp16      1.2 MB
  fp16_t* cb = Wx;  // c aliases Wx: Wx[batch] dead after GEMM2[batch]
  const long long avail = (long long)ws_size - (long long)(p - (char*)d_ws);

  // ---- input prep ----
  split_hilo<<<(unsigned)(BS * D / 4 / 256), 256, 0, stream>>>(
      x, xh, xl, (int)(BS * D / 4));
  cast_f32_f16<<<(unsigned)(D * D / 4 / 256), 256, 0, stream>>>(
      W, Wh, (int)(D * D / 4));
  cast_f32_f16<<<(unsigned)(D * D / 4 / 256), 256, 0, stream>>>(
      pw, ph, (int)(D * D / 4));
  transpose_sd<<<dim3(24, 64, 8), 256, 0, stream>>>(xh, xT);

  // GEMM1 (2-term): Wx = (x_hi + x_lo) @ W^T, fp16 out.  768 blocks = 3/CU.
  gemm_bt<true, false, EPI_F16><<<dim3(6, 128, 1), 256, 0, stream>>>(
      xh, xl, Wh, nullptr, Wx, 768, 0, 0, 0, nullptr, nullptr, 0);

  // ---- attention middle: GEMM2 -> softmax -> GEMM3, chunked to fit ws ----
  const long long perb = S * S * 4 + S * S * 2;  // s fp32 + a fp16 per batch

  if (avail >= perb) {
    int nb = (int)(avail / perb);
    if (nb > 8) nb = 8;
    char* q = p;
    float*  sb = (float*)q; q += (long long)nb * S * S * 4;
    fp16_t* ab = (fp16_t*)q;

    for (int c0 = 0; c0 < 8; c0 += nb) {
      const int n = (8 - c0) < nb ? (8 - c0) : nb;
      // GEMM2 (1-term): s = Wx @ x_hi^T per batch, fp32 out
      gemm_bt<false, false, EPI_F32><<<dim3(16, 16, n), 256, 0, stream>>>(
          Wx + (long long)c0 * S * D, nullptr, xh + (long long)c0 * S * D,
          nullptr, sb, 768, S * D, S * D, S * S, nullptr, nullptr, 0);
      softmax_rows<<<(unsigned)(n * S), 256, 0, stream>>>(sb, ab, 0);
      // GEMM3: c = a @ x  (fp16 out, aliases Wx)
      gemm_bt<false, false, EPI_F16><<<dim3(6, 16, n), 256, 0, stream>>>(
          ab, nullptr, xT + (long long)c0 * D * S, nullptr,
          cb + (long long)c0 * S * D, 2048,
          S * S, D * S, S * D, nullptr, nullptr, 0);
    }
  } else {
    // row-chunk fallback: R rows (multiple of 128) within one batch
    long long R = (avail / 12288) & ~127LL;  // 8192 B (s) + 4096 B (a) per row
    if (R < 128) R = 128;
    if (R > 2048) R = 2048;
    char* q = p;
    float*  sb = (float*)q; q += R * S * 4;
    fp16_t* ab = (fp16_t*)q;
    for (int b = 0; b < 8; b++) {
      for (long long r0 = 0; r0 < S; r0 += R) {
        const long long rows = (S - r0) < R ? (S - r0) : R;
        const unsigned gy = (unsigned)(rows / 128);
        gemm_bt<false, false, EPI_F32><<<dim3(16, gy, 1), 256, 0, stream>>>(
            Wx + ((long long)b * S + r0) * D, nullptr,
            xh + (long long)b * S * D, nullptr, sb, 768,
            0, 0, 0, nullptr, nullptr, 0);
        softmax_rows<<<(unsigned)rows, 256, 0, stream>>>(sb, ab, (int)r0);
        gemm_bt<false, false, EPI_F16><<<dim3(6, gy, 1), 256, 0, stream>>>(
            ab, nullptr, xT + (long long)b * D * S, nullptr,
            cb + ((long long)b * S + r0) * D, 2048,
            0, 0, 0, nullptr, nullptr, 0);
      }
    }
  }

  // GEMM4 (full): out = x + relu(c @ proj_w^T + pb).  768 blocks = 3/CU.
  gemm_bt<false, false, EPI_FUSE><<<dim3(6, 128, 1), 256, 0, stream>>>(
      cb, nullptr, ph, nullptr, (float*)d_out, 768, 0, 0, 0, pb, x, 0);
}

// Round 7
// 431.751 us; speedup vs baseline: 1.5518x; 1.1495x over previous
//
#include <hip/hip_runtime.h>
#include <hip/hip_bf16.h>

typedef _Float16 fp16_t;
typedef __attribute__((ext_vector_type(8))) _Float16 fp16x8;
typedef __attribute__((ext_vector_type(4))) _Float16 fp16x4;
typedef __attribute__((ext_vector_type(4))) float fx4;

#define GLDS(g, l)                                                              \
  __builtin_amdgcn_global_load_lds(                                             \
      (const __attribute__((address_space(1))) void*)(g),                       \
      (__attribute__((address_space(3))) void*)(l), 16, 0, 0)

enum { EPI_F32 = 0, EPI_F16 = 1, EPI_FUSE = 2 };

// ---------------------------------------------------------------------------
// XCD-aware block remap. HW assigns blocks to XCDs round-robin by linear id;
// we invert that so blocks sharing an A-strip (same by,bz; all bx) run
// consecutively on ONE XCD -> A-strip re-reads hit that XCD's L2.
// Requires gridDim.y*gridDim.z divisible by 8 (all our grids satisfy this).
// ---------------------------------------------------------------------------
__device__ __forceinline__ void xcd_decode(int& bx, int& by, int& bz) {
  const int nx = gridDim.x, ny = gridDim.y;
  const int lid = (int)(blockIdx.x + nx * (blockIdx.y + ny * blockIdx.z));
  const int j = lid & 7, k = lid >> 3;
  bx = k % nx;
  const int s = j + 8 * (k / nx);
  by = s % ny;
  bz = s / ny;
}

// ---------------------------------------------------------------------------
// BT-layout fp16 GEMM: C = A1·B1^T (+ A2·B1^T if ASPLIT)
// A: [M,K] row-major, B: [N,K] row-major. Tile 128x128, BK=32, 4 waves.
// global_load_lds staging with bank-conflict swizzle (verified: 0 conflicts).
// ---------------------------------------------------------------------------
template <bool ASPLIT, int EPI>
__global__ __launch_bounds__(256) void gemm_bt(
    const fp16_t* __restrict__ A1, const fp16_t* __restrict__ A2,
    const fp16_t* __restrict__ B1, void* __restrict__ Cv, int K,
    long long sA, long long sB, long long sC,
    const float* __restrict__ bias, const float* __restrict__ resid) {
  constexpr int ALO = ASPLIT ? 128 * 32 : 0;
  __shared__ __align__(16) fp16_t As[128 * 32 + ALO];
  __shared__ __align__(16) fp16_t Bs[128 * 32];

  const int tid  = threadIdx.x;
  const int lane = tid & 63;
  const int w    = tid >> 6;
  const int wr   = w >> 1;
  const int wc   = w & 1;

  int bx, by, bz;
  xcd_decode(bx, by, bz);
  const int N = (int)gridDim.x * 128;
  const long long tile_m = (long long)by * 128;
  const long long tile_n = (long long)bx * 128;
  const long long z = bz;
  const long long aoff = z * sA + tile_m * (long long)K;
  const long long boff = z * sB + tile_n * (long long)K;

  fx4 acc[4][4];
#pragma unroll
  for (int i = 0; i < 4; i++)
#pragma unroll
    for (int j = 0; j < 4; j++) acc[i][j] = (fx4){0.f, 0.f, 0.f, 0.f};

  // staging swizzle: LDS slot m holds global chunk (m+(r>>1))&3 of row r
  const int r_l = lane >> 2;
  const int c_l = ((((lane & 3) + ((r_l >> 1) & 3)) & 3) << 3);
  const int frow = lane & 15;
  const int qoff = (((lane >> 4) - ((frow >> 1) & 3)) & 3) << 3;

  const size_t sa0 = (size_t)(w * 16 + r_l) * K + c_l;
  const size_t sa1 = (size_t)(64 + w * 16 + r_l) * K + c_l;
  const int ld0 = (w * 16) * 32;
  const int ld1 = (64 + w * 16) * 32;

  for (int kt = 0; kt < K; kt += 32) {
    __syncthreads();
    {
      const fp16_t* gah = A1 + aoff + kt;
      const fp16_t* gbh = B1 + boff + kt;
      GLDS(gah + sa0, &As[ld0]);
      GLDS(gah + sa1, &As[ld1]);
      GLDS(gbh + sa0, &Bs[ld0]);
      GLDS(gbh + sa1, &Bs[ld1]);
      if (ASPLIT) {
        const fp16_t* gal = A2 + aoff + kt;
        GLDS(gal + sa0, &As[ALO + ld0]);
        GLDS(gal + sa1, &As[ALO + ld1]);
      }
    }
    __syncthreads();

    fp16x8 afh[4], bbh[4], afl[4];
#pragma unroll
    for (int mi = 0; mi < 4; mi++)
      afh[mi] = *(const fp16x8*)&As[(wr * 64 + mi * 16 + frow) * 32 + qoff];
#pragma unroll
    for (int ni = 0; ni < 4; ni++)
      bbh[ni] = *(const fp16x8*)&Bs[(wc * 64 + ni * 16 + frow) * 32 + qoff];
    if (ASPLIT) {
#pragma unroll
      for (int mi = 0; mi < 4; mi++)
        afl[mi] =
            *(const fp16x8*)&As[ALO + (wr * 64 + mi * 16 + frow) * 32 + qoff];
    }

#pragma unroll
    for (int mi = 0; mi < 4; mi++)
#pragma unroll
      for (int ni = 0; ni < 4; ni++) {
        fx4 a = acc[mi][ni];
        a = __builtin_amdgcn_mfma_f32_16x16x32_f16(afh[mi], bbh[ni], a, 0, 0, 0);
        if (ASPLIT)
          a = __builtin_amdgcn_mfma_f32_16x16x32_f16(afl[mi], bbh[ni], a, 0, 0, 0);
        acc[mi][ni] = a;
      }
  }

  // Epilogue. C/D layout: col = lane&15, row = (lane>>4)*4 + reg  [m89/m91]
  const int er = (lane >> 4) * 4;
  const int ec = lane & 15;
  const long long crow = tile_m + wr * 64;
  const long long ccol = tile_n + wc * 64;

#pragma unroll
  for (int mi = 0; mi < 4; mi++)
#pragma unroll
    for (int j = 0; j < 4; j++) {
      const long long r = crow + mi * 16 + er + j;
#pragma unroll
      for (int ni = 0; ni < 4; ni++) {
        const long long cc = ccol + ni * 16 + ec;
        const long long idx = z * sC + r * N + cc;
        const float v = acc[mi][ni][j];
        if (EPI == EPI_F32) {
          ((float*)Cv)[idx] = v;
        } else if (EPI == EPI_F16) {
          ((fp16_t*)Cv)[idx] = (fp16_t)v;
        } else {  // EPI_FUSE
          float u = v + bias[cc];
          u = u > 0.f ? u : 0.f;
          ((float*)Cv)[idx] = resid[r * N + cc] + u;
        }
      }
    }
}

// ---------------------------------------------------------------------------
// Fused softmax+PV GEMM: C[m,d] = sum_t softmax(s)[m,t] * xT[d,t]
// A-tile is NOT materialized: staged from s (fp32) with exp(s-m)*invl and
// diagonal zeroing applied in registers, then ds_write into the same
// swizzled LDS layout the fragment reads expect. B side = GLDS as usual.
// Grid (6, 16, nbatch). K = 2048 (full t range).
// ---------------------------------------------------------------------------
__global__ __launch_bounds__(256) void gemm_pv(
    const float* __restrict__ Sc, const float* __restrict__ rm,
    const float* __restrict__ ril, const fp16_t* __restrict__ Bx,
    fp16_t* __restrict__ C) {
  __shared__ __align__(16) fp16_t As[128 * 32];
  __shared__ __align__(16) fp16_t Bs[128 * 32];

  const int tid  = threadIdx.x;
  const int lane = tid & 63;
  const int w    = tid >> 6;
  const int wr   = w >> 1;
  const int wc   = w & 1;

  int bx, by, bz;
  xcd_decode(bx, by, bz);
  const long long tile_m = (long long)by * 128;
  const long long tile_n = (long long)bx * 128;
  const long long z = bz;

  fx4 acc[4][4];
#pragma unroll
  for (int i = 0; i < 4; i++)
#pragma unroll
    for (int j = 0; j < 4; j++) acc[i][j] = (fx4){0.f, 0.f, 0.f, 0.f};

  // B staging (GLDS, swizzled), K = 2048
  const int r_l = lane >> 2;
  const int c_l = ((((lane & 3) + ((r_l >> 1) & 3)) & 3) << 3);
  const int frow = lane & 15;
  const int qoff = (((lane >> 4) - ((frow >> 1) & 3)) & 3) << 3;
  const size_t sb0 = (size_t)(w * 16 + r_l) * 2048 + c_l;
  const size_t sb1 = (size_t)(64 + w * 16 + r_l) * 2048 + c_l;
  const int ld0 = (w * 16) * 32;
  const int ld1 = (64 + w * 16) * 32;
  const fp16_t* B = Bx + z * (768LL * 2048) + tile_n * 2048;

  // A side: thread -> (row r, half hh); covers 16 floats = chunks 2hh, 2hh+1
  const int r = tid >> 1, hh = tid & 1;
  const int gm = (int)tile_m + r;  // row within batch
  const float mrow = rm[z * 2048 + gm];
  const float il = ril[z * 2048 + gm];
  const float* srow =
      Sc + z * (2048LL * 2048) + (long long)gm * 2048 + hh * 16;
  // global chunk q of row r lives at LDS slot (q-(r>>1))&3
  const int slot0 = ((2 * hh + 0) - ((r >> 1) & 3)) & 3;
  const int slot1 = ((2 * hh + 1) - ((r >> 1) & 3)) & 3;
  fp16_t* const wp0 = &As[r * 32 + slot0 * 8];
  fp16_t* const wp1 = &As[r * 32 + slot1 * 8];

  for (int kt = 0; kt < 2048; kt += 32) {
    const float4* sv = (const float4*)(srow + kt);
    const float4 u0 = sv[0], u1 = sv[1], u2 = sv[2], u3 = sv[3];
    const float va[16] = {u0.x, u0.y, u0.z, u0.w, u1.x, u1.y, u1.z, u1.w,
                          u2.x, u2.y, u2.z, u2.w, u3.x, u3.y, u3.z, u3.w};
    fp16x8 c0, c1;
#pragma unroll
    for (int i = 0; i < 16; i++) {
      const int tc = kt + hh * 16 + i;
      float e = __expf(va[i] - mrow) * il;
      if (tc == gm) e = 0.f;  // diagonal mask
      if (i < 8) c0[i] = (fp16_t)e;
      else       c1[i - 8] = (fp16_t)e;
    }
    __syncthreads();  // previous iter's fragment reads done
    *(fp16x8*)wp0 = c0;
    *(fp16x8*)wp1 = c1;
    GLDS(B + kt + sb0, &Bs[ld0]);
    GLDS(B + kt + sb1, &Bs[ld1]);
    __syncthreads();  // drains lgkm (ds_write) + vm (GLDS)

    fp16x8 af[4], bb[4];
#pragma unroll
    for (int mi = 0; mi < 4; mi++)
      af[mi] = *(const fp16x8*)&As[(wr * 64 + mi * 16 + frow) * 32 + qoff];
#pragma unroll
    for (int ni = 0; ni < 4; ni++)
      bb[ni] = *(const fp16x8*)&Bs[(wc * 64 + ni * 16 + frow) * 32 + qoff];
#pragma unroll
    for (int mi = 0; mi < 4; mi++)
#pragma unroll
      for (int ni = 0; ni < 4; ni++)
        acc[mi][ni] = __builtin_amdgcn_mfma_f32_16x16x32_f16(
            af[mi], bb[ni], acc[mi][ni], 0, 0, 0);
  }

  const int er = (lane >> 4) * 4;
  const int ec = lane & 15;
  const long long crow = tile_m + wr * 64;
  const long long ccol = tile_n + wc * 64;
  fp16_t* Cz = C + z * (2048LL * 768);
#pragma unroll
  for (int mi = 0; mi < 4; mi++)
#pragma unroll
    for (int j = 0; j < 4; j++) {
      const long long rr = crow + mi * 16 + er + j;
#pragma unroll
      for (int ni = 0; ni < 4; ni++)
        Cz[rr * 768 + ccol + ni * 16 + ec] = (fp16_t)acc[mi][ni][j];
    }
}

// ---------------------------------------------------------------------------
// Per-row stats of s: m = max (diag masked), invl = 1/sum(exp(s-m)).
// One 256-thread block per row.
// ---------------------------------------------------------------------------
__global__ __launch_bounds__(256) void rowstat(
    const float* __restrict__ s, float* __restrict__ rm,
    float* __restrict__ ril) {
  __shared__ float red[8];
  const int row = blockIdx.x;
  const int m = row & 2047;  // diagonal position (chunks are whole batches)
  const float4* sr = (const float4*)(s + (long long)row * 2048);
  const int lane = threadIdx.x & 63;
  const int w = threadIdx.x >> 6;
  const int t0 = threadIdx.x * 8;

  const float4 u0 = sr[threadIdx.x * 2];
  const float4 u1 = sr[threadIdx.x * 2 + 1];
  float v[8] = {u0.x, u0.y, u0.z, u0.w, u1.x, u1.y, u1.z, u1.w};

  float mx = -1e30f;
#pragma unroll
  for (int j = 0; j < 8; j++) {
    if (t0 + j == m) v[j] = -1e30f;
    mx = fmaxf(mx, v[j]);
  }
  for (int o = 32; o > 0; o >>= 1) mx = fmaxf(mx, __shfl_down(mx, o, 64));
  if (lane == 0) red[w] = mx;
  __syncthreads();
  mx = fmaxf(fmaxf(red[0], red[1]), fmaxf(red[2], red[3]));

  float sum = 0.f;
#pragma unroll
  for (int j = 0; j < 8; j++) sum += __expf(v[j] - mx);
  for (int o = 32; o > 0; o >>= 1) sum += __shfl_down(sum, o, 64);
  if (lane == 0) red[4 + w] = sum;
  __syncthreads();
  if (threadIdx.x == 0) {
    const float total = red[4] + red[5] + red[6] + red[7];
    rm[row] = mx;
    ril[row] = 1.0f / total;
  }
}

// ---------------------------------------------------------------------------
// Fused prep: x fp32 -> xh, xl (hi/lo fp16, row-major) + xT (hi, transposed)
// ---------------------------------------------------------------------------
__global__ __launch_bounds__(256) void prep_x(
    const float* __restrict__ x, fp16_t* __restrict__ xh,
    fp16_t* __restrict__ xl, fp16_t* __restrict__ xT) {
  __shared__ fp16_t t[32][33];
  const int b = blockIdx.z;
  const int d0 = blockIdx.x * 32;
  const int s0 = blockIdx.y * 32;
  const float* ib = x + (long long)b * 2048 * 768;
  const int tx = threadIdx.x & 31;
  const int ty = threadIdx.x >> 5;
#pragma unroll
  for (int i = 0; i < 4; i++) {
    const int srow = s0 + ty + i * 8;
    const long long idx = (long long)b * 2048 * 768 + (long long)srow * 768 + d0 + tx;
    const float v = ib[(long long)srow * 768 + d0 + tx];
    const fp16_t h = (fp16_t)v;
    xh[idx] = h;
    xl[idx] = (fp16_t)(v - (float)h);
    t[ty + i * 8][tx] = h;
  }
  __syncthreads();
#pragma unroll
  for (int i = 0; i < 4; i++)
    xT[(long long)b * 768 * 2048 + (long long)(d0 + ty + i * 8) * 2048 + s0 + tx] =
        t[tx][ty + i * 8];
}

// ---------------------------------------------------------------------------
__global__ __launch_bounds__(256) void cast_f32_f16(
    const float* __restrict__ in, fp16_t* __restrict__ out, int n4) {
  const int i = blockIdx.x * 256 + threadIdx.x;
  if (i >= n4) return;
  const float4 v = ((const float4*)in)[i];
  ((fp16x4*)out)[i] =
      (fp16x4){(fp16_t)v.x, (fp16_t)v.y, (fp16_t)v.z, (fp16_t)v.w};
}

// ---------------------------------------------------------------------------
extern "C" void kernel_launch(void* const* d_in, const int* in_sizes, int n_in,
                              void* d_out, int out_size, void* d_ws,
                              size_t ws_size, hipStream_t stream) {
  const float* x  = (const float*)d_in[0];
  const float* W  = (const float*)d_in[1];
  const float* pw = (const float*)d_in[2];
  const float* pb = (const float*)d_in[3];

  const long long S = 2048, D = 768;
  const long long BS = 8 * S;

  // ---- fixed workspace (~103.4 MB) ----
  char* p = (char*)d_ws;
  auto carve = [&](long long bytes) {
    char* q = p;
    p += (bytes + 255) & ~255LL;
    return q;
  };
  fp16_t* xh = (fp16_t*)carve(BS * D * 2);   // x hi           25.2 MB
  fp16_t* xl = (fp16_t*)carve(BS * D * 2);   // x lo (G1 only) 25.2 MB
  fp16_t* xT = (fp16_t*)carve(BS * D * 2);   // x^T (hi)       25.2 MB
  fp16_t* Wx = (fp16_t*)carve(BS * D * 2);   // Wx fp16 / c    25.2 MB
  fp16_t* Wh = (fp16_t*)carve(D * D * 2);    // W fp16          1.2 MB
  fp16_t* ph = (fp16_t*)carve(D * D * 2);    // proj_w fp16     1.2 MB
  float*  rm  = (float*)carve(BS * 4);       // row max         64 KB
  float*  ril = (float*)carve(BS * 4);       // row 1/sum       64 KB
  fp16_t* cb = Wx;  // c aliases Wx: Wx[batch] dead after GEMM2[batch]
  const long long avail = (long long)ws_size - (long long)(p - (char*)d_ws);

  // ---- prep ----
  prep_x<<<dim3(24, 64, 8), 256, 0, stream>>>(x, xh, xl, xT);
  cast_f32_f16<<<(unsigned)(D * D / 4 / 256), 256, 0, stream>>>(
      W, Wh, (int)(D * D / 4));
  cast_f32_f16<<<(unsigned)(D * D / 4 / 256), 256, 0, stream>>>(
      pw, ph, (int)(D * D / 4));

  // GEMM1 (2-term): Wx = (x_hi + x_lo) @ W^T, fp16 out
  gemm_bt<true, EPI_F16><<<dim3(6, 128, 1), 256, 0, stream>>>(
      xh, xl, Wh, Wx, 768, 0, 0, 0, nullptr, nullptr);

  // ---- attention middle, chunked over whole batches (ws≈268MB -> nb=8) ----
  const long long perb = S * S * 4;  // s fp32 per batch = 16.78 MB
  int nb = (int)(avail / perb);
  if (nb < 1) nb = 1;
  if (nb > 8) nb = 8;
  float* sb = (float*)p;

  for (int c0 = 0; c0 < 8; c0 += nb) {
    const int n = (8 - c0) < nb ? (8 - c0) : nb;
    // GEMM2: s = Wx @ x_hi^T per batch, fp32 out
    gemm_bt<false, EPI_F32><<<dim3(16, 16, n), 256, 0, stream>>>(
        Wx + (long long)c0 * S * D, nullptr, xh + (long long)c0 * S * D,
        sb, 768, S * D, S * D, S * S, nullptr, nullptr);
    // row stats (max, 1/sum) with diagonal mask
    rowstat<<<(unsigned)(n * S), 256, 0, stream>>>(sb, rm, ril);
    // fused softmax+PV: c = softmax(s) @ x
    gemm_pv<<<dim3(6, 16, n), 256, 0, stream>>>(
        sb, rm, ril, xT + (long long)c0 * D * S, cb + (long long)c0 * S * D);
  }

  // GEMM4: out = x + relu(c @ proj_w^T + pb), fp32
  gemm_bt<false, EPI_FUSE><<<dim3(6, 128, 1), 256, 0, stream>>>(
      cb, nullptr, ph, (float*)d_out, 768, 0, 0, 0, pb, x);
}